// Round 1
// baseline (508.568 us; speedup 1.0000x reference)
//
#include <hip/hip_runtime.h>
#include <math.h>

#define S 8192
#define D 768
#define NA 256
#define NO 256
#define MAXW 40
#define NCAT 13
#define NPOL 3
#define NPROJ (2 + NCAT + NPOL)   // 18 projection columns: [valid0,valid1, cat0..12, pol0..2]

// ---------------------------------------------------------------------------
// Kernel 1: per-span max-pool over word_rep rows + double-precision projection
// partials.  One block per span (0..255 aspects, 256..511 opinions).
// rep_out: [512][768] fp32 ; proj_out: [512][18] double
// ---------------------------------------------------------------------------
__global__ __launch_bounds__(256) void span_pool_proj(
    const float* __restrict__ word_rep,
    const int*   __restrict__ aspects,
    const int*   __restrict__ opinions,
    const float* __restrict__ W_valid,   // (1536,2) row-major
    const float* __restrict__ W_cat,     // (1536,13)
    const float* __restrict__ W_pol,     // (1536,3)
    float*  __restrict__ rep_out,
    double* __restrict__ proj_out)
{
    __shared__ float rep[D];
    const int b = blockIdx.x;     // 0..511
    const int t = threadIdx.x;    // 0..255

    const int* spans = (b < NA) ? aspects : opinions;
    const int  s     = (b < NA) ? b : (b - NA);
    const int  woff  = (b < NA) ? 0 : D;   // aspects use W rows [0,768), opinions [768,1536)

    const int head  = spans[2 * s];
    const int tail  = spans[2 * s + 1];
    const int width = tail - head;         // 1..40, spans never exceed S (head <= S-MAXW-1)

    float m0 = -3.402823466e+38f, m1 = m0, m2 = m0;
    const float* base = word_rep + (size_t)head * D;
    for (int r = 0; r < width; ++r) {
        const float* row = base + (size_t)r * D;
        m0 = fmaxf(m0, row[t]);
        m1 = fmaxf(m1, row[t + 256]);
        m2 = fmaxf(m2, row[t + 512]);
    }
    rep[t] = m0; rep[t + 256] = m1; rep[t + 512] = m2;
    float* orow = rep_out + (size_t)b * D;
    orow[t] = m0; orow[t + 256] = m1; orow[t + 512] = m2;
    __syncthreads();

    if (t < NPROJ) {
        const float* W; int ncol, col;
        if (t < 2)           { W = W_valid; ncol = 2;    col = t; }
        else if (t < 2+NCAT) { W = W_cat;   ncol = NCAT; col = t - 2; }
        else                 { W = W_pol;   ncol = NPOL; col = t - 2 - NCAT; }
        double acc = 0.0;
        for (int d = 0; d < D; ++d)
            acc += (double)rep[d] * (double)W[(size_t)(woff + d) * ncol + col];
        proj_out[(size_t)b * NPROJ + t] = acc;
    }
}

// ---------------------------------------------------------------------------
// Kernel 2: one block per (aspect i, opinion j) pair, p = i*256 + j.
// Writes the masked 1536-float pair_reps row (384 float4 lanes) plus the
// small outputs.  Entire d_out is fp32 (ints/bool stored as float values).
// ---------------------------------------------------------------------------
__global__ __launch_bounds__(384) void pair_write(
    const float4* __restrict__ rep4,     // 512 rows x 192 float4
    const double* __restrict__ proj,     // 512 x 18
    const float*  __restrict__ b_valid,  // (2,)
    const float*  __restrict__ b_cat,    // (13,)
    const float*  __restrict__ b_pol,    // (3,)
    float* __restrict__ out)
{
    const int p = blockIdx.x;   // 0..65535
    const int i = p >> 8;       // aspect id (j varies fastest -> L2 locality on rep rows)
    const int j = p & 255;      // opinion id
    const int t = threadIdx.x;  // 0..383

    __shared__ int smask;
    const double* pa = proj + (size_t)i * NPROJ;
    const double* po = proj + (size_t)(NA + j) * NPROJ;

    if (t == 0) {
        double v0 = pa[0] + po[0] + (double)b_valid[0];
        double v1 = pa[1] + po[1] + (double)b_valid[1];
        smask = (v0 > v1) ? 1 : 0;
    }
    __syncthreads();
    const int mask = smask;

    // --- out0: where(mask, [asp_rep[i] | opi_rep[j]], 0)  (402.6 MB total) ---
    float4 val;
    if (mask) {
        val = (t < 192) ? rep4[(size_t)i * 192 + t]
                        : rep4[(size_t)(NA + j) * 192 + (t - 192)];
    } else {
        val = make_float4(0.f, 0.f, 0.f, 0.f);
    }
    ((float4*)out)[(size_t)p * 384 + t] = val;

    // --- small outputs (flat fp32, concatenated in reference return order) ---
    const size_t OFF1 = (size_t)NA * NO * 2 * D;            // asp_ids
    const size_t OFF2 = OFF1 + (size_t)NA * NO;             // opi_ids
    const size_t OFF3 = OFF2 + (size_t)NA * NO;             // cate_out
    const size_t OFF4 = OFF3 + (size_t)NA * NO * NCAT;      // polar_out
    const size_t OFF5 = OFF4 + (size_t)NA * NO * NPOL;      // valid_mask

    if (t == 0) {
        out[OFF1 + p] = mask ? (float)i : -1.0f;
        out[OFF2 + p] = mask ? (float)j : -1.0f;
        out[OFF5 + p] = mask ? 1.0f : 0.0f;
    } else if (t >= 64 && t < 64 + NCAT) {
        const int c = t - 64;
        float v = mask ? (float)(pa[2 + c] + po[2 + c] + (double)b_cat[c]) : 0.0f;
        out[OFF3 + (size_t)p * NCAT + c] = v;
    } else if (t >= 128 && t < 128 + NPOL) {
        const int c = t - 128;
        float v = mask ? (float)(pa[2 + NCAT + c] + po[2 + NCAT + c] + (double)b_pol[c]) : 0.0f;
        out[OFF4 + (size_t)p * NPOL + c] = v;
    }
}

extern "C" void kernel_launch(void* const* d_in, const int* in_sizes, int n_in,
                              void* d_out, int out_size, void* d_ws, size_t ws_size,
                              hipStream_t stream)
{
    const float* word_rep = (const float*)d_in[0];   // (8192,768)
    const int*   aspects  = (const int*)  d_in[1];   // (256,2)
    const int*   opinions = (const int*)  d_in[2];   // (256,2)
    const float* W_valid  = (const float*)d_in[3];   // (1536,2)
    const float* b_valid  = (const float*)d_in[4];   // (2,)
    const float* W_cat    = (const float*)d_in[5];   // (1536,13)
    const float* b_cat    = (const float*)d_in[6];   // (13,)
    const float* W_pol    = (const float*)d_in[7];   // (1536,3)
    const float* b_pol    = (const float*)d_in[8];   // (3,)
    float* out = (float*)d_out;

    // workspace: reps (512*768 fp32 = 1.5 MB) then projections (512*18 f64)
    float*  rep  = (float*)d_ws;
    double* proj = (double*)((char*)d_ws + (size_t)(NA + NO) * D * sizeof(float));

    span_pool_proj<<<NA + NO, 256, 0, stream>>>(
        word_rep, aspects, opinions, W_valid, W_cat, W_pol, rep, proj);

    pair_write<<<NA * NO, 384, 0, stream>>>(
        (const float4*)rep, proj, b_valid, b_cat, b_pol, out);
}

// Round 3
// 476.567 us; speedup vs baseline: 1.0671x; 1.0671x over previous
//
#include <hip/hip_runtime.h>
#include <math.h>

#define S 8192
#define D 768
#define NA 256
#define NO 256
#define MAXW 40
#define NCAT 13
#define NPOL 3
#define NPROJ (2 + NCAT + NPOL)   // 18 projection columns: [valid0,valid1, cat0..12, pol0..2]

// out layout (flat fp32, reference return order)
#define OFF1 ((size_t)NA * NO * 2 * D)            // asp_ids
#define OFF2 (OFF1 + (size_t)NA * NO)             // opi_ids
#define OFF3 (OFF2 + (size_t)NA * NO)             // cate_out
#define OFF4 (OFF3 + (size_t)NA * NO * NCAT)      // polar_out
#define OFF5 (OFF4 + (size_t)NA * NO * NPOL)      // valid_mask

typedef float vfloat4 __attribute__((ext_vector_type(4)));  // native vector: ok for nontemporal builtins

// ---------------------------------------------------------------------------
// Kernel 1: per-span max-pool (float4 loads, 192 active lanes) + double-
// precision projection partials. One block per span (0..255 asp, 256..511 opi).
// ---------------------------------------------------------------------------
__global__ __launch_bounds__(256) void span_pool_proj(
    const float* __restrict__ word_rep,
    const int*   __restrict__ aspects,
    const int*   __restrict__ opinions,
    const float* __restrict__ W_valid,   // (1536,2) row-major
    const float* __restrict__ W_cat,     // (1536,13)
    const float* __restrict__ W_pol,     // (1536,3)
    float*  __restrict__ rep_out,
    double* __restrict__ proj_out)
{
    __shared__ float rep[D];
    const int b = blockIdx.x;     // 0..511
    const int t = threadIdx.x;    // 0..255

    const int* spans = (b < NA) ? aspects : opinions;
    const int  s     = (b < NA) ? b : (b - NA);
    const int  woff  = (b < NA) ? 0 : D;

    const int head  = spans[2 * s];
    const int tail  = spans[2 * s + 1];
    const int width = tail - head;         // 1..40; all rows in-bounds (head <= S-MAXW-1)

    if (t < 192) {
        const vfloat4* base = (const vfloat4*)(word_rep + (size_t)head * D) + t;
        vfloat4 m = base[0];
        for (int r = 1; r < width; ++r) {
            vfloat4 v = base[(size_t)r * (D / 4)];
            m.x = fmaxf(m.x, v.x); m.y = fmaxf(m.y, v.y);
            m.z = fmaxf(m.z, v.z); m.w = fmaxf(m.w, v.w);
        }
        ((vfloat4*)rep)[t] = m;
        ((vfloat4*)(rep_out + (size_t)b * D))[t] = m;
    }
    __syncthreads();

    if (t < NPROJ) {
        const float* W; int ncol, col;
        if (t < 2)             { W = W_valid; ncol = 2;    col = t; }
        else if (t < 2 + NCAT) { W = W_cat;   ncol = NCAT; col = t - 2; }
        else                   { W = W_pol;   ncol = NPOL; col = t - 2 - NCAT; }
        double a0 = 0.0, a1 = 0.0;   // 2 accumulators to break the dep chain
        for (int d = 0; d < D; d += 2) {
            a0 += (double)rep[d]     * (double)W[(size_t)(woff + d)     * ncol + col];
            a1 += (double)rep[d + 1] * (double)W[(size_t)(woff + d + 1) * ncol + col];
        }
        proj_out[(size_t)b * NPROJ + t] = a0 + a1;
    }
}

// ---------------------------------------------------------------------------
// Kernel 2: per-pair mask + small outputs. Grid 256 blocks (i) x 256 thr (j).
// Writes mask[p] to ws for the streaming kernel.
// ---------------------------------------------------------------------------
__global__ __launch_bounds__(256) void pair_small(
    const double* __restrict__ proj,     // 512 x 18
    const float*  __restrict__ b_valid,
    const float*  __restrict__ b_cat,
    const float*  __restrict__ b_pol,
    float*    __restrict__ out,
    unsigned* __restrict__ maskbuf)
{
    const int i = blockIdx.x;
    const int j = threadIdx.x;
    const int p = (i << 8) | j;

    const double* pa = proj + (size_t)i * NPROJ;          // wave-uniform -> scalar loads
    const double* po = proj + (size_t)(NA + j) * NPROJ;

    const double v0 = pa[0] + po[0] + (double)b_valid[0];
    const double v1 = pa[1] + po[1] + (double)b_valid[1];
    const int mask = (v0 > v1) ? 1 : 0;

    maskbuf[p] = (unsigned)mask;
    out[OFF1 + p] = mask ? (float)i : -1.0f;
    out[OFF2 + p] = mask ? (float)j : -1.0f;
    out[OFF5 + p] = mask ? 1.0f : 0.0f;
#pragma unroll
    for (int c = 0; c < NCAT; ++c) {
        float v = mask ? (float)(pa[2 + c] + po[2 + c] + (double)b_cat[c]) : 0.0f;
        out[OFF3 + (size_t)p * NCAT + c] = v;
    }
#pragma unroll
    for (int c = 0; c < NPOL; ++c) {
        float v = mask ? (float)(pa[2 + NCAT + c] + po[2 + NCAT + c] + (double)b_pol[c]) : 0.0f;
        out[OFF4 + (size_t)p * NPOL + c] = v;
    }
}

// ---------------------------------------------------------------------------
// Kernel 3: pure streaming write of out0 (402.6 MB). One block per pair,
// 384 lanes x float4. No LDS, no sync; mask is a wave-uniform scalar load.
// ---------------------------------------------------------------------------
__global__ __launch_bounds__(384) void pair_stream(
    const vfloat4*  __restrict__ rep4,     // 512 rows x 192 float4
    const unsigned* __restrict__ maskbuf,
    vfloat4*        __restrict__ out4)
{
    const int p = blockIdx.x;   // 0..65535
    const int t = threadIdx.x;  // 0..383
    const int i = p >> 8;
    const int j = p & 255;

    vfloat4 val = (vfloat4)0.f;
    if (maskbuf[p]) {
        val = (t < 192) ? rep4[(size_t)i * 192 + t]
                        : rep4[(size_t)(NA + j) * 192 + (t - 192)];
    }
    __builtin_nontemporal_store(val, &out4[(size_t)p * 384 + t]);
}

extern "C" void kernel_launch(void* const* d_in, const int* in_sizes, int n_in,
                              void* d_out, int out_size, void* d_ws, size_t ws_size,
                              hipStream_t stream)
{
    const float* word_rep = (const float*)d_in[0];   // (8192,768)
    const int*   aspects  = (const int*)  d_in[1];   // (256,2)
    const int*   opinions = (const int*)  d_in[2];   // (256,2)
    const float* W_valid  = (const float*)d_in[3];   // (1536,2)
    const float* b_valid  = (const float*)d_in[4];   // (2,)
    const float* W_cat    = (const float*)d_in[5];   // (1536,13)
    const float* b_cat    = (const float*)d_in[6];   // (13,)
    const float* W_pol    = (const float*)d_in[7];   // (1536,3)
    const float* b_pol    = (const float*)d_in[8];   // (3,)
    float* out = (float*)d_out;

    // ws layout: rep (512*768 f32 = 1.5 MB) | proj (512*18 f64) | mask (64K u32)
    float*    rep  = (float*)d_ws;
    double*   proj = (double*)((char*)d_ws + (size_t)(NA + NO) * D * sizeof(float));
    unsigned* mask = (unsigned*)((char*)proj + (size_t)(NA + NO) * NPROJ * sizeof(double));

    span_pool_proj<<<NA + NO, 256, 0, stream>>>(
        word_rep, aspects, opinions, W_valid, W_cat, W_pol, rep, proj);

    pair_small<<<NA, NO, 0, stream>>>(proj, b_valid, b_cat, b_pol, out, mask);

    pair_stream<<<NA * NO, 384, 0, stream>>>((const vfloat4*)rep, mask, (vfloat4*)out);
}